// Round 7
// baseline (179.446 us; speedup 1.0000x reference)
//
#include <hip/hip_runtime.h>
#include <cmath>

#define NWALK 4096
#define NXD   48
#define HID   256
#define WPB   8
#define GCONST 0.7978845608028654f

typedef _Float16 half8   __attribute__((ext_vector_type(8)));
typedef float    float4v __attribute__((ext_vector_type(4)));

// ---------- prep_all: blocks 0..15: W2 transpose->fp16 + W1 cast; blocks 16..271: layer-1
__global__ __launch_bounds__(256) void prep_all(const float* __restrict__ W2,
                                                const float* __restrict__ W1,
                                                const float* __restrict__ x,
                                                const float* __restrict__ b1,
                                                _Float16* __restrict__ W2c,
                                                _Float16* __restrict__ W1c,
                                                _Float16* __restrict__ t1h,
                                                _Float16* __restrict__ h1h,
                                                _Float16* __restrict__ ch) {
    __shared__ float tile[64][65];
    __shared__ float xs[16][NXD];

    if (blockIdx.x < 16) {
        const int bi = blockIdx.x & 3;
        const int bj = blockIdx.x >> 2;
        const int tx = threadIdx.x & 63;
        const int ty = threadIdx.x >> 6;
        #pragma unroll
        for (int r = 0; r < 16; ++r) {
            int il = ty * 16 + r;
            tile[tx][il] = W2[(bi * 64 + il) * HID + bj * 64 + tx];
        }
        __syncthreads();
        #pragma unroll
        for (int r = 0; r < 16; ++r) {
            int jl = ty * 16 + r;
            W2c[(bj * 64 + jl) * HID + bi * 64 + tx] = (_Float16)tile[jl][tx];
        }
        #pragma unroll
        for (int r = 0; r < 3; ++r) {
            int k = blockIdx.x * 3 + r;
            W1c[k * HID + threadIdx.x] = (_Float16)W1[k * HID + threadIdx.x];
        }
    } else {
        const int i  = threadIdx.x;
        const int w0 = (blockIdx.x - 16) * 16;

        float col[NXD];
        float S = 0.f;
        #pragma unroll
        for (int k = 0; k < NXD; ++k) {
            float v = W1[k * HID + i];
            col[k] = v;
            S = fmaf(v, v, S);
        }
        #pragma unroll
        for (int t = threadIdx.x; t < 16 * NXD; t += 256)
            ((float*)xs)[t] = x[w0 * NXD + t];
        __syncthreads();

        const float b = b1[i];
        #pragma unroll 4
        for (int w = 0; w < 16; ++w) {
            float a1 = b;
            #pragma unroll
            for (int k = 0; k < NXD; ++k)
                a1 = fmaf(xs[w][k], col[k], a1);
            float h1 = tanhf(a1);
            float t1 = 1.f - h1 * h1;
            int off = (w0 + w) * HID + i;
            t1h[off] = (_Float16)t1;
            h1h[off] = (_Float16)h1;
            ch[off]  = (_Float16)(S * h1 * t1);
        }
    }
}

// ---------- eloc8: 8 walkers/block, streamed A with correct distance-1 prefetch
__global__ __launch_bounds__(256, 2) void eloc8(
    const float* __restrict__ x,
    const float* __restrict__ b2,
    const float* __restrict__ w3,
    const _Float16* __restrict__ W2c,
    const _Float16* __restrict__ W1c,
    const _Float16* __restrict__ t1h,
    const _Float16* __restrict__ h1h,
    const _Float16* __restrict__ ch,
    float* __restrict__ out)
{
    __shared__ __align__(16) _Float16 AsT[2][50 * HID];   // 51.2 KB, walker-parity
    __shared__ float xs[WPB][NXD];
    __shared__ float b2s[HID], w3s[HID];
    __shared__ float a2s[HID], ps[HID], us[HID], uh2s[HID];  // wave-local use
    __shared__ float gw[2][4][NXD];                       // parity-buffered
    __shared__ float wred[2][4][2];                       // parity-buffered

    const int w0   = blockIdx.x * WPB;
    const int tid  = threadIdx.x;
    const int wave = tid >> 6;
    const int lane = tid & 63;
    const int n16  = lane & 15;
    const int quad = lane >> 4;
    const int ci   = tid & 31;     // staging i-chunk
    const int k0   = tid >> 5;     // staging k-row base

    // A-fragment base pointers (walker-independent)
    const _Float16* apB[4];
    #pragma unroll
    for (int a = 0; a < 4; ++a)
        apB[a] = W2c + ((wave * 4 + a) * 16 + n16) * HID + quad * 8;

    // W1c staging chunks resident (walker-independent, 24 regs)
    half8 w1r[6];
    #pragma unroll
    for (int s2 = 0; s2 < 6; ++s2)
        w1r[s2] = *(const half8*)(W1c + (s2 * 8 + k0) * HID + ci * 8);

    // preload step-0 A fragments (latency overlaps staging below)
    half8 afs[2][4];
    #pragma unroll
    for (int a = 0; a < 4; ++a) afs[0][a] = *(const half8*)(apB[a]);

    // block-constant staging
    b2s[tid] = b2[tid];
    w3s[tid] = w3[tid];
    #pragma unroll
    for (int t = tid; t < WPB * NXD; t += 256)
        ((float*)xs)[t] = x[w0 * NXD + t];

    // stage walker 0 into buffer 0
    {
        half8 th = *(const half8*)(t1h + w0 * HID + ci * 8);
        #pragma unroll
        for (int s2 = 0; s2 < 6; ++s2) {
            int k = s2 * 8 + k0;
            *(half8*)(AsT[0] + k * HID + ((ci ^ (k & 7)) * 8)) = w1r[s2] * th;
        }
        if (tid < 32) {
            half8 hv = *(const half8*)(h1h + w0 * HID + tid * 8);
            *(half8*)(AsT[0] + 48 * HID + tid * 8) = hv;                  // 48&7=0
        } else if (tid < 64) {
            int c2 = tid - 32;
            half8 cv = *(const half8*)(ch + w0 * HID + c2 * 8);
            *(half8*)(AsT[0] + 49 * HID + ((c2 ^ 1) * 8)) = cv;           // 49&7=1
        }
    }
    __syncthreads();

    for (int ww = 0; ww < WPB; ++ww) {
        const int cur = ww & 1, nxt = cur ^ 1;
        const int wg  = w0 + ww;
        const _Float16* curA = AsT[cur];
        const bool more = (ww + 1 < WPB);

        // early loads for next walker's staging (latency overlaps MFMA)
        half8 th, hv, cv;
        if (more) {
            const int wn = wg + 1;
            th = *(const half8*)(t1h + wn * HID + ci * 8);
            if (tid < 32)      hv = *(const half8*)(h1h + wn * HID + tid * 8);
            else if (tid < 64) cv = *(const half8*)(ch + wn * HID + (tid - 32) * 8);
        }

        // ---- MFMA loop: distance-1 double-buffered A stream ----
        float4v acc[4][4];
        #pragma unroll
        for (int a = 0; a < 4; ++a)
            #pragma unroll
            for (int kt = 0; kt < 4; ++kt)
                acc[a][kt] = (float4v){0.f, 0.f, 0.f, 0.f};

        #pragma unroll
        for (int s = 0; s < 8; ++s) {
            // prefetch step s+1 (wraps to step 0 for the next walker at s==7)
            if (s < 7 || more) {
                const int sn = (s + 1) & 7;
                #pragma unroll
                for (int a = 0; a < 4; ++a)
                    afs[(s + 1) & 1][a] = *(const half8*)(apB[a] + sn * 32);
            }
            half8 bf[4];
            #pragma unroll
            for (int kt = 0; kt < 4; ++kt) {
                int krow = (kt < 3) ? (kt * 16 + n16) : (48 + (n16 & 1));
                int goff = krow * HID + ((((s * 4 + quad) ^ (krow & 7)) << 3));
                bf[kt] = *(const half8*)(curA + goff);
            }
            #pragma unroll
            for (int a = 0; a < 4; ++a) {
                half8 av = afs[s & 1][a];
                #pragma unroll
                for (int kt = 0; kt < 4; ++kt)
                    acc[a][kt] = __builtin_amdgcn_mfma_f32_16x16x32_f16(
                        av, bf[kt], acc[a][kt], 0, 0, 0);
            }
        }

        // ---- staging writes for next walker (other buffer) ----
        if (more) {
            #pragma unroll
            for (int s2 = 0; s2 < 6; ++s2) {
                int k = s2 * 8 + k0;
                *(half8*)(AsT[nxt] + k * HID + ((ci ^ (k & 7)) * 8)) = w1r[s2] * th;
            }
            if (tid < 32)      *(half8*)(AsT[nxt] + 48 * HID + tid * 8) = hv;
            else if (tid < 64) *(half8*)(AsT[nxt] + 49 * HID + (((tid - 32) ^ 1) * 8)) = cv;
        }

        // ---- a2/p scatter (wave-local) ----
        if (n16 == 0) {
            #pragma unroll
            for (int a = 0; a < 4; ++a)
                #pragma unroll
                for (int reg = 0; reg < 4; ++reg)
                    a2s[(wave * 4 + a) * 16 + quad * 4 + reg] = acc[a][3][reg];
        } else if (n16 == 1) {
            #pragma unroll
            for (int a = 0; a < 4; ++a)
                #pragma unroll
                for (int reg = 0; reg < 4; ++reg)
                    ps[(wave * 4 + a) * 16 + quad * 4 + reg] = acc[a][3][reg];
        }

        // ---- distributed activation: 1 tanh per thread (wave-local LDS) ----
        float a2v = a2s[tid] + b2s[tid];
        float h2  = tanhf(a2v);
        float t2  = 1.f - h2 * h2;
        float u   = w3s[tid] * t2;
        us[tid]   = u;
        uh2s[tid] = u * h2;
        float rt2 = u * ps[tid];

        // ---- T1 / g ----
        float rt1 = 0.f;
        float gp[3] = {0.f, 0.f, 0.f};
        #pragma unroll
        for (int a = 0; a < 4; ++a) {
            #pragma unroll
            for (int reg = 0; reg < 4; ++reg) {
                int j = (wave * 4 + a) * 16 + quad * 4 + reg;
                float uh2 = uh2s[j];
                float uu  = us[j];
                #pragma unroll
                for (int kt = 0; kt < 3; ++kt) {
                    float m = acc[a][kt][reg];
                    rt1    = fmaf(m * m, uh2, rt1);
                    gp[kt] = fmaf(m, uu, gp[kt]);
                }
            }
        }
        #pragma unroll
        for (int off = 32; off > 0; off >>= 1) {
            rt1 += __shfl_down(rt1, off, 64);
            rt2 += __shfl_down(rt2, off, 64);
        }
        #pragma unroll
        for (int kt = 0; kt < 3; ++kt) {
            gp[kt] += __shfl_xor(gp[kt], 16, 64);
            gp[kt] += __shfl_xor(gp[kt], 32, 64);
        }
        if (lane == 0) { wred[cur][wave][0] = rt1; wred[cur][wave][1] = rt2; }
        if (lane < 16) {
            #pragma unroll
            for (int kt = 0; kt < 3; ++kt) gw[cur][wave][kt * 16 + lane] = gp[kt];
        }

        __syncthreads();   // AsT[nxt] ready; gw/wred[cur] ready

        // ---- final combine for walker ww (wave 0; parity protects) ----
        if (wave == 0) {
            float ggp = 0.f, potp = 0.f;
            if (lane < NXD) {
                float g = gw[cur][0][lane] + gw[cur][1][lane]
                        + gw[cur][2][lane] + gw[cur][3][lane];
                ggp = g * g;
                float xq = xs[ww][lane];
                potp = 0.5f * xq * xq;
            }
            #pragma unroll
            for (int off = 32; off > 0; off >>= 1) {
                ggp  += __shfl_down(ggp, off, 64);
                potp += __shfl_down(potp, off, 64);
            }
            if (lane == 0) {
                float T1 = wred[cur][0][0] + wred[cur][1][0] + wred[cur][2][0] + wred[cur][3][0];
                float T2 = wred[cur][0][1] + wred[cur][1][1] + wred[cur][2][1] + wred[cur][3][1];
                float kin = T1 + T2 - 0.5f * ggp;

                float x0 = xs[ww][0], x1 = xs[ww][1], x2 = xs[ww][2];
                float x3 = xs[ww][3], x4 = xs[ww][4], x5 = xs[ww][5];
                float d01 = (x0-x1)*(x0-x1) + (x2-x1)*(x2-x1);
                float d02 = (x0-x2)*(x0-x2) + (x1-x2)*(x1-x2);
                float d12 = (x3-x5)*(x3-x5) + (x4-x5)*(x4-x5);
                float inter = GCONST * (expf(-2.f*d01) + expf(-2.f*d02) + expf(-2.f*d12));

                out[wg]             = kin + potp + inter;
                out[NWALK + wg]     = kin;
                out[2 * NWALK + wg] = potp;
                out[3 * NWALK + wg] = inter;
            }
        }
    }
}

extern "C" void kernel_launch(void* const* d_in, const int* in_sizes, int n_in,
                              void* d_out, int out_size, void* d_ws, size_t ws_size,
                              hipStream_t stream) {
    const float* x  = (const float*)d_in[0];
    const float* W1 = (const float*)d_in[1];
    const float* b1 = (const float*)d_in[2];
    const float* W2 = (const float*)d_in[3];
    const float* b2 = (const float*)d_in[4];
    const float* w3 = (const float*)d_in[5];
    float* out = (float*)d_out;

    char* ws = (char*)d_ws;
    _Float16* W2c = (_Float16*)(ws);                       // 128 KB
    _Float16* W1c = (_Float16*)(ws + 131072);              // 24 KB
    _Float16* t1h = (_Float16*)(ws + 155648);              // 2 MB
    _Float16* h1h = (_Float16*)(ws + 2252800);             // 2 MB
    _Float16* chv = (_Float16*)(ws + 4349952);             // 2 MB

    prep_all<<<16 + NWALK / 16, 256, 0, stream>>>(W2, W1, x, b1, W2c, W1c, t1h, h1h, chv);
    eloc8<<<NWALK / WPB, 256, 0, stream>>>(x, b2, w3, W2c, W1c, t1h, h1h, chv, out);
}

// Round 8
// 176.610 us; speedup vs baseline: 1.0161x; 1.0161x over previous
//
#include <hip/hip_runtime.h>
#include <cmath>

#define NWALK 4096
#define NXD   48
#define HID   256
#define WPB   8
#define GCONST 0.7978845608028654f

typedef _Float16 half8   __attribute__((ext_vector_type(8)));
typedef float    float4v __attribute__((ext_vector_type(4)));

// ---------- prep_all: blocks 0..15: W2 transpose->fp16 + W1 cast; blocks 16..271: layer-1
__global__ __launch_bounds__(256) void prep_all(const float* __restrict__ W2,
                                                const float* __restrict__ W1,
                                                const float* __restrict__ x,
                                                const float* __restrict__ b1,
                                                _Float16* __restrict__ W2c,
                                                _Float16* __restrict__ W1c,
                                                _Float16* __restrict__ t1h,
                                                _Float16* __restrict__ h1h,
                                                _Float16* __restrict__ ch) {
    __shared__ float tile[64][65];
    __shared__ float xs[16][NXD];

    if (blockIdx.x < 16) {
        const int bi = blockIdx.x & 3;
        const int bj = blockIdx.x >> 2;
        const int tx = threadIdx.x & 63;
        const int ty = threadIdx.x >> 6;
        #pragma unroll
        for (int r = 0; r < 16; ++r) {
            int il = ty * 16 + r;
            tile[tx][il] = W2[(bi * 64 + il) * HID + bj * 64 + tx];
        }
        __syncthreads();
        #pragma unroll
        for (int r = 0; r < 16; ++r) {
            int jl = ty * 16 + r;
            W2c[(bj * 64 + jl) * HID + bi * 64 + tx] = (_Float16)tile[jl][tx];
        }
        #pragma unroll
        for (int r = 0; r < 3; ++r) {
            int k = blockIdx.x * 3 + r;
            W1c[k * HID + threadIdx.x] = (_Float16)W1[k * HID + threadIdx.x];
        }
    } else {
        const int i  = threadIdx.x;
        const int w0 = (blockIdx.x - 16) * 16;

        float col[NXD];
        float S = 0.f;
        #pragma unroll
        for (int k = 0; k < NXD; ++k) {
            float v = W1[k * HID + i];
            col[k] = v;
            S = fmaf(v, v, S);
        }
        #pragma unroll
        for (int t = threadIdx.x; t < 16 * NXD; t += 256)
            ((float*)xs)[t] = x[w0 * NXD + t];
        __syncthreads();

        const float b = b1[i];
        #pragma unroll 4
        for (int w = 0; w < 16; ++w) {
            float a1 = b;
            #pragma unroll
            for (int k = 0; k < NXD; ++k)
                a1 = fmaf(xs[w][k], col[k], a1);
            float h1 = tanhf(a1);
            float t1 = 1.f - h1 * h1;
            int off = (w0 + w) * HID + i;
            t1h[off] = (_Float16)t1;
            h1h[off] = (_Float16)h1;
            ch[off]  = (_Float16)(S * h1 * t1);
        }
    }
}

// ---------- eloc8: 8 walkers/block, FULL A-residency (all 8 K-steps in registers)
__global__ __launch_bounds__(256, 2) void eloc8(
    const float* __restrict__ x,
    const float* __restrict__ b2,
    const float* __restrict__ w3,
    const _Float16* __restrict__ W2c,
    const _Float16* __restrict__ W1c,
    const _Float16* __restrict__ t1h,
    const _Float16* __restrict__ h1h,
    const _Float16* __restrict__ ch,
    float* __restrict__ out)
{
    __shared__ __align__(16) _Float16 AsT[2][50 * HID];   // 51.2 KB, walker-parity
    __shared__ float xs[WPB][NXD];
    __shared__ float b2s[HID], w3s[HID];
    __shared__ float a2s[HID], ps[HID], us[HID], uh2s[HID];  // wave-local use
    __shared__ float gw[2][4][NXD];                       // parity-buffered
    __shared__ float wred[2][4][2];                       // parity-buffered

    const int w0   = blockIdx.x * WPB;
    const int tid  = threadIdx.x;
    const int wave = tid >> 6;
    const int lane = tid & 63;
    const int n16  = lane & 15;
    const int quad = tid >> 4 & 3;
    const int ci   = tid & 31;     // staging i-chunk
    const int k0   = tid >> 5;     // staging k-row base

    // ---- FULL A-residency: all 8 steps x 4 j-tiles = 128 regs, loaded ONCE ----
    half8 afr[8][4];
    #pragma unroll
    for (int s = 0; s < 8; ++s)
        #pragma unroll
        for (int a = 0; a < 4; ++a)
            afr[s][a] = *(const half8*)(W2c + ((wave * 4 + a) * 16 + n16) * HID
                                        + s * 32 + quad * 8);

    // block-constant staging
    b2s[tid] = b2[tid];
    w3s[tid] = w3[tid];
    #pragma unroll
    for (int t = tid; t < WPB * NXD; t += 256)
        ((float*)xs)[t] = x[w0 * NXD + t];

    // stage walker 0 into buffer 0 (W1c reloaded from L2 — not register-resident)
    {
        half8 th = *(const half8*)(t1h + w0 * HID + ci * 8);
        #pragma unroll
        for (int s2 = 0; s2 < 6; ++s2) {
            int k = s2 * 8 + k0;
            half8 wv = *(const half8*)(W1c + k * HID + ci * 8);
            *(half8*)(AsT[0] + k * HID + ((ci ^ (k & 7)) * 8)) = wv * th;
        }
        if (tid < 32) {
            half8 hv = *(const half8*)(h1h + w0 * HID + tid * 8);
            *(half8*)(AsT[0] + 48 * HID + tid * 8) = hv;                  // 48&7=0
        } else if (tid < 64) {
            int c2 = tid - 32;
            half8 cv = *(const half8*)(ch + w0 * HID + c2 * 8);
            *(half8*)(AsT[0] + 49 * HID + ((c2 ^ 1) * 8)) = cv;           // 49&7=1
        }
    }
    __syncthreads();

    for (int ww = 0; ww < WPB; ++ww) {
        const int cur = ww & 1, nxt = cur ^ 1;
        const int wg  = w0 + ww;
        const _Float16* curA = AsT[cur];
        const bool more = (ww + 1 < WPB);

        // ---- MFMA loop: pure LDS + resident A — no global traffic ----
        float4v acc[4][4];
        #pragma unroll
        for (int a = 0; a < 4; ++a)
            #pragma unroll
            for (int kt = 0; kt < 4; ++kt)
                acc[a][kt] = (float4v){0.f, 0.f, 0.f, 0.f};

        #pragma unroll
        for (int s = 0; s < 8; ++s) {
            half8 bf[4];
            #pragma unroll
            for (int kt = 0; kt < 4; ++kt) {
                int krow = (kt < 3) ? (kt * 16 + n16) : (48 + (n16 & 1));
                int goff = krow * HID + ((((s * 4 + quad) ^ (krow & 7)) << 3));
                bf[kt] = *(const half8*)(curA + goff);
            }
            #pragma unroll
            for (int a = 0; a < 4; ++a)
                #pragma unroll
                for (int kt = 0; kt < 4; ++kt)
                    acc[a][kt] = __builtin_amdgcn_mfma_f32_16x16x32_f16(
                        afr[s][a], bf[kt], acc[a][kt], 0, 0, 0);
        }

        // ---- stage next walker into other buffer (loads issued here, short-lived) ----
        if (more) {
            const int wn = wg + 1;
            half8 th = *(const half8*)(t1h + wn * HID + ci * 8);
            #pragma unroll
            for (int s2 = 0; s2 < 6; ++s2) {
                int k = s2 * 8 + k0;
                half8 wv = *(const half8*)(W1c + k * HID + ci * 8);
                *(half8*)(AsT[nxt] + k * HID + ((ci ^ (k & 7)) * 8)) = wv * th;
            }
            if (tid < 32) {
                half8 hv = *(const half8*)(h1h + wn * HID + tid * 8);
                *(half8*)(AsT[nxt] + 48 * HID + tid * 8) = hv;
            } else if (tid < 64) {
                half8 cv = *(const half8*)(ch + wn * HID + (tid - 32) * 8);
                *(half8*)(AsT[nxt] + 49 * HID + (((tid - 32) ^ 1) * 8)) = cv;
            }
        }

        // ---- a2/p scatter (wave-local) ----
        if (n16 == 0) {
            #pragma unroll
            for (int a = 0; a < 4; ++a)
                #pragma unroll
                for (int reg = 0; reg < 4; ++reg)
                    a2s[(wave * 4 + a) * 16 + quad * 4 + reg] = acc[a][3][reg];
        } else if (n16 == 1) {
            #pragma unroll
            for (int a = 0; a < 4; ++a)
                #pragma unroll
                for (int reg = 0; reg < 4; ++reg)
                    ps[(wave * 4 + a) * 16 + quad * 4 + reg] = acc[a][3][reg];
        }

        // ---- distributed activation: 1 tanh per thread (wave-local LDS) ----
        float a2v = a2s[tid] + b2s[tid];
        float h2  = tanhf(a2v);
        float t2  = 1.f - h2 * h2;
        float u   = w3s[tid] * t2;
        us[tid]   = u;
        uh2s[tid] = u * h2;
        float rt2 = u * ps[tid];

        // ---- T1 / g ----
        float rt1 = 0.f;
        float gp[3] = {0.f, 0.f, 0.f};
        #pragma unroll
        for (int a = 0; a < 4; ++a) {
            #pragma unroll
            for (int reg = 0; reg < 4; ++reg) {
                int j = (wave * 4 + a) * 16 + quad * 4 + reg;
                float uh2 = uh2s[j];
                float uu  = us[j];
                #pragma unroll
                for (int kt = 0; kt < 3; ++kt) {
                    float m = acc[a][kt][reg];
                    rt1    = fmaf(m * m, uh2, rt1);
                    gp[kt] = fmaf(m, uu, gp[kt]);
                }
            }
        }
        #pragma unroll
        for (int off = 32; off > 0; off >>= 1) {
            rt1 += __shfl_down(rt1, off, 64);
            rt2 += __shfl_down(rt2, off, 64);
        }
        #pragma unroll
        for (int kt = 0; kt < 3; ++kt) {
            gp[kt] += __shfl_xor(gp[kt], 16, 64);
            gp[kt] += __shfl_xor(gp[kt], 32, 64);
        }
        if (lane == 0) { wred[cur][wave][0] = rt1; wred[cur][wave][1] = rt2; }
        if (lane < 16) {
            #pragma unroll
            for (int kt = 0; kt < 3; ++kt) gw[cur][wave][kt * 16 + lane] = gp[kt];
        }

        __syncthreads();   // AsT[nxt] ready; gw/wred[cur] ready

        // ---- final combine for walker ww (wave 0; parity protects) ----
        if (wave == 0) {
            float ggp = 0.f, potp = 0.f;
            if (lane < NXD) {
                float g = gw[cur][0][lane] + gw[cur][1][lane]
                        + gw[cur][2][lane] + gw[cur][3][lane];
                ggp = g * g;
                float xq = xs[ww][lane];
                potp = 0.5f * xq * xq;
            }
            #pragma unroll
            for (int off = 32; off > 0; off >>= 1) {
                ggp  += __shfl_down(ggp, off, 64);
                potp += __shfl_down(potp, off, 64);
            }
            if (lane == 0) {
                float T1 = wred[cur][0][0] + wred[cur][1][0] + wred[cur][2][0] + wred[cur][3][0];
                float T2 = wred[cur][0][1] + wred[cur][1][1] + wred[cur][2][1] + wred[cur][3][1];
                float kin = T1 + T2 - 0.5f * ggp;

                float x0 = xs[ww][0], x1 = xs[ww][1], x2 = xs[ww][2];
                float x3 = xs[ww][3], x4 = xs[ww][4], x5 = xs[ww][5];
                float d01 = (x0-x1)*(x0-x1) + (x2-x1)*(x2-x1);
                float d02 = (x0-x2)*(x0-x2) + (x1-x2)*(x1-x2);
                float d12 = (x3-x5)*(x3-x5) + (x4-x5)*(x4-x5);
                float inter = GCONST * (expf(-2.f*d01) + expf(-2.f*d02) + expf(-2.f*d12));

                out[wg]             = kin + potp + inter;
                out[NWALK + wg]     = kin;
                out[2 * NWALK + wg] = potp;
                out[3 * NWALK + wg] = inter;
            }
        }
    }
}

extern "C" void kernel_launch(void* const* d_in, const int* in_sizes, int n_in,
                              void* d_out, int out_size, void* d_ws, size_t ws_size,
                              hipStream_t stream) {
    const float* x  = (const float*)d_in[0];
    const float* W1 = (const float*)d_in[1];
    const float* b1 = (const float*)d_in[2];
    const float* W2 = (const float*)d_in[3];
    const float* b2 = (const float*)d_in[4];
    const float* w3 = (const float*)d_in[5];
    float* out = (float*)d_out;

    char* ws = (char*)d_ws;
    _Float16* W2c = (_Float16*)(ws);                       // 128 KB
    _Float16* W1c = (_Float16*)(ws + 131072);              // 24 KB
    _Float16* t1h = (_Float16*)(ws + 155648);              // 2 MB
    _Float16* h1h = (_Float16*)(ws + 2252800);             // 2 MB
    _Float16* chv = (_Float16*)(ws + 4349952);             // 2 MB

    prep_all<<<16 + NWALK / 16, 256, 0, stream>>>(W2, W1, x, b1, W2c, W1c, t1h, h1h, chv);
    eloc8<<<NWALK / WPB, 256, 0, stream>>>(x, b2, w3, W2c, W1c, t1h, h1h, chv, out);
}

// Round 9
// 120.325 us; speedup vs baseline: 1.4913x; 1.4678x over previous
//
#include <hip/hip_runtime.h>
#include <cmath>

#define NWALK 4096
#define NXD   48
#define HID   256
#define WPB   8
#define GCONST 0.7978845608028654f

typedef _Float16 half8   __attribute__((ext_vector_type(8)));
typedef float    float4v __attribute__((ext_vector_type(4)));

// ---------- prep_all: blocks 0..15: W2 transpose->fp16 + W1 cast; blocks 16..271: layer-1
__global__ __launch_bounds__(256) void prep_all(const float* __restrict__ W2,
                                                const float* __restrict__ W1,
                                                const float* __restrict__ x,
                                                const float* __restrict__ b1,
                                                _Float16* __restrict__ W2c,
                                                _Float16* __restrict__ W1c,
                                                _Float16* __restrict__ t1h,
                                                _Float16* __restrict__ h1h,
                                                _Float16* __restrict__ ch) {
    __shared__ float tile[64][65];
    __shared__ float xs[16][NXD];

    if (blockIdx.x < 16) {
        const int bi = blockIdx.x & 3;
        const int bj = blockIdx.x >> 2;
        const int tx = threadIdx.x & 63;
        const int ty = threadIdx.x >> 6;
        #pragma unroll
        for (int r = 0; r < 16; ++r) {
            int il = ty * 16 + r;
            tile[tx][il] = W2[(bi * 64 + il) * HID + bj * 64 + tx];
        }
        __syncthreads();
        #pragma unroll
        for (int r = 0; r < 16; ++r) {
            int jl = ty * 16 + r;
            W2c[(bj * 64 + jl) * HID + bi * 64 + tx] = (_Float16)tile[jl][tx];
        }
        #pragma unroll
        for (int r = 0; r < 3; ++r) {
            int k = blockIdx.x * 3 + r;
            W1c[k * HID + threadIdx.x] = (_Float16)W1[k * HID + threadIdx.x];
        }
    } else {
        const int i  = threadIdx.x;
        const int w0 = (blockIdx.x - 16) * 16;

        float col[NXD];
        float S = 0.f;
        #pragma unroll
        for (int k = 0; k < NXD; ++k) {
            float v = W1[k * HID + i];
            col[k] = v;
            S = fmaf(v, v, S);
        }
        #pragma unroll
        for (int t = threadIdx.x; t < 16 * NXD; t += 256)
            ((float*)xs)[t] = x[w0 * NXD + t];
        __syncthreads();

        const float b = b1[i];
        #pragma unroll 4
        for (int w = 0; w < 16; ++w) {
            float a1 = b;
            #pragma unroll
            for (int k = 0; k < NXD; ++k)
                a1 = fmaf(xs[w][k], col[k], a1);
            float h1 = tanhf(a1);
            float t1 = 1.f - h1 * h1;
            int off = (w0 + w) * HID + i;
            t1h[off] = (_Float16)t1;
            h1h[off] = (_Float16)h1;
            ch[off]  = (_Float16)(S * h1 * t1);
        }
    }
}

// ---------- eloc8: full A-residency + kt-split passes (16-reg accumulator)
__global__ __launch_bounds__(256, 2) void eloc8(
    const float* __restrict__ x,
    const float* __restrict__ b2,
    const float* __restrict__ w3,
    const _Float16* __restrict__ W2c,
    const _Float16* __restrict__ W1c,
    const _Float16* __restrict__ t1h,
    const _Float16* __restrict__ h1h,
    const _Float16* __restrict__ ch,
    float* __restrict__ out)
{
    __shared__ __align__(16) _Float16 AsT[2][50 * HID];   // 51.2 KB, walker-parity
    __shared__ float xs[WPB][NXD];
    __shared__ float b2s[HID], w3s[HID];
    __shared__ float a2s[HID], ps[HID], us[HID], uh2s[HID];  // wave-local use
    __shared__ float gw[2][4][NXD];                       // parity-buffered
    __shared__ float wred[2][4][2];                       // parity-buffered

    const int w0   = blockIdx.x * WPB;
    const int tid  = threadIdx.x;
    const int wave = tid >> 6;
    const int lane = tid & 63;
    const int n16  = lane & 15;
    const int quad = (tid >> 4) & 3;
    const int ci   = tid & 31;     // staging i-chunk
    const int k0   = tid >> 5;     // staging k-row base

    // ---- FULL A-residency: 8 steps x 4 j-tiles = 128 regs, loaded ONCE ----
    half8 afr[8][4];
    #pragma unroll
    for (int s = 0; s < 8; ++s)
        #pragma unroll
        for (int a = 0; a < 4; ++a)
            afr[s][a] = *(const half8*)(W2c + ((wave * 4 + a) * 16 + n16) * HID
                                        + s * 32 + quad * 8);

    // block-constant staging
    b2s[tid] = b2[tid];
    w3s[tid] = w3[tid];
    #pragma unroll
    for (int t = tid; t < WPB * NXD; t += 256)
        ((float*)xs)[t] = x[w0 * NXD + t];

    // stage walker 0 into buffer 0
    {
        half8 th = *(const half8*)(t1h + w0 * HID + ci * 8);
        #pragma unroll
        for (int s2 = 0; s2 < 6; ++s2) {
            int k = s2 * 8 + k0;
            half8 wv = *(const half8*)(W1c + k * HID + ci * 8);
            *(half8*)(AsT[0] + k * HID + ((ci ^ (k & 7)) * 8)) = wv * th;
        }
        if (tid < 32) {
            half8 hv = *(const half8*)(h1h + w0 * HID + tid * 8);
            *(half8*)(AsT[0] + 48 * HID + tid * 8) = hv;                  // 48&7=0
        } else if (tid < 64) {
            int c2 = tid - 32;
            half8 cv = *(const half8*)(ch + w0 * HID + c2 * 8);
            *(half8*)(AsT[0] + 49 * HID + ((c2 ^ 1) * 8)) = cv;           // 49&7=1
        }
    }
    __syncthreads();

    for (int ww = 0; ww < WPB; ++ww) {
        const int cur = ww & 1, nxt = cur ^ 1;
        const int wg  = w0 + ww;
        const _Float16* curA = AsT[cur];
        const bool more = (ww + 1 < WPB);

        // ---- pass kt=3 first: a2 (col 0) / p (col 1) ----
        {
            float4v acc[4];
            #pragma unroll
            for (int a = 0; a < 4; ++a) acc[a] = (float4v){0.f, 0.f, 0.f, 0.f};
            const int krow = 48 + (n16 & 1);
            #pragma unroll
            for (int s = 0; s < 8; ++s) {
                half8 bf = *(const half8*)(curA + krow * HID
                            + ((((s * 4 + quad) ^ (krow & 7)) << 3)));
                #pragma unroll
                for (int a = 0; a < 4; ++a)
                    acc[a] = __builtin_amdgcn_mfma_f32_16x16x32_f16(
                        afr[s][a], bf, acc[a], 0, 0, 0);
            }
            if (n16 == 0) {
                #pragma unroll
                for (int a = 0; a < 4; ++a)
                    #pragma unroll
                    for (int reg = 0; reg < 4; ++reg)
                        a2s[(wave * 4 + a) * 16 + quad * 4 + reg] = acc[a][reg];
            } else if (n16 == 1) {
                #pragma unroll
                for (int a = 0; a < 4; ++a)
                    #pragma unroll
                    for (int reg = 0; reg < 4; ++reg)
                        ps[(wave * 4 + a) * 16 + quad * 4 + reg] = acc[a][reg];
            }
        }

        // ---- distributed activation: 1 tanh per thread (wave-local LDS) ----
        float a2v = a2s[tid] + b2s[tid];
        float h2  = tanhf(a2v);
        float t2  = 1.f - h2 * h2;
        float u   = w3s[tid] * t2;
        us[tid]   = u;
        uh2s[tid] = u * h2;
        float rt2 = u * ps[tid];

        // preload the 16 (u, u*h2) values this thread folds against (32 regs)
        float uu_r[4][4], uh_r[4][4];
        #pragma unroll
        for (int a = 0; a < 4; ++a)
            #pragma unroll
            for (int reg = 0; reg < 4; ++reg) {
                int j = (wave * 4 + a) * 16 + quad * 4 + reg;
                uu_r[a][reg] = us[j];
                uh_r[a][reg] = uh2s[j];
            }

        // ---- kt = 0..2 passes, 16-reg accumulator reused, immediate fold ----
        float rt1 = 0.f;
        float gp[3];
        #pragma unroll 1
        for (int kt = 0; kt < 3; ++kt) {
            float4v acc[4];
            #pragma unroll
            for (int a = 0; a < 4; ++a) acc[a] = (float4v){0.f, 0.f, 0.f, 0.f};
            const int krow = kt * 16 + n16;
            #pragma unroll
            for (int s = 0; s < 8; ++s) {
                half8 bf = *(const half8*)(curA + krow * HID
                            + ((((s * 4 + quad) ^ (krow & 7)) << 3)));
                #pragma unroll
                for (int a = 0; a < 4; ++a)
                    acc[a] = __builtin_amdgcn_mfma_f32_16x16x32_f16(
                        afr[s][a], bf, acc[a], 0, 0, 0);
            }
            float g = 0.f;
            #pragma unroll
            for (int a = 0; a < 4; ++a)
                #pragma unroll
                for (int reg = 0; reg < 4; ++reg) {
                    float m = acc[a][reg];
                    rt1 = fmaf(m * m, uh_r[a][reg], rt1);
                    g   = fmaf(m, uu_r[a][reg], g);
                }
            gp[kt] = g;
        }

        // ---- stage next walker into other buffer ----
        if (more) {
            const int wn = wg + 1;
            half8 th = *(const half8*)(t1h + wn * HID + ci * 8);
            #pragma unroll
            for (int s2 = 0; s2 < 6; ++s2) {
                int k = s2 * 8 + k0;
                half8 wv = *(const half8*)(W1c + k * HID + ci * 8);
                *(half8*)(AsT[nxt] + k * HID + ((ci ^ (k & 7)) * 8)) = wv * th;
            }
            if (tid < 32) {
                half8 hv = *(const half8*)(h1h + wn * HID + tid * 8);
                *(half8*)(AsT[nxt] + 48 * HID + tid * 8) = hv;
            } else if (tid < 64) {
                half8 cv = *(const half8*)(ch + wn * HID + (tid - 32) * 8);
                *(half8*)(AsT[nxt] + 49 * HID + (((tid - 32) ^ 1) * 8)) = cv;
            }
        }

        // ---- reductions ----
        #pragma unroll
        for (int off = 32; off > 0; off >>= 1) {
            rt1 += __shfl_down(rt1, off, 64);
            rt2 += __shfl_down(rt2, off, 64);
        }
        #pragma unroll
        for (int kt = 0; kt < 3; ++kt) {
            gp[kt] += __shfl_xor(gp[kt], 16, 64);
            gp[kt] += __shfl_xor(gp[kt], 32, 64);
        }
        if (lane == 0) { wred[cur][wave][0] = rt1; wred[cur][wave][1] = rt2; }
        if (lane < 16) {
            #pragma unroll
            for (int kt = 0; kt < 3; ++kt) gw[cur][wave][kt * 16 + lane] = gp[kt];
        }

        __syncthreads();   // AsT[nxt] ready; gw/wred[cur] ready

        // ---- final combine for walker ww (wave 0; parity protects) ----
        if (wave == 0) {
            float ggp = 0.f, potp = 0.f;
            if (lane < NXD) {
                float g = gw[cur][0][lane] + gw[cur][1][lane]
                        + gw[cur][2][lane] + gw[cur][3][lane];
                ggp = g * g;
                float xq = xs[ww][lane];
                potp = 0.5f * xq * xq;
            }
            #pragma unroll
            for (int off = 32; off > 0; off >>= 1) {
                ggp  += __shfl_down(ggp, off, 64);
                potp += __shfl_down(potp, off, 64);
            }
            if (lane == 0) {
                float T1 = wred[cur][0][0] + wred[cur][1][0] + wred[cur][2][0] + wred[cur][3][0];
                float T2 = wred[cur][0][1] + wred[cur][1][1] + wred[cur][2][1] + wred[cur][3][1];
                float kin = T1 + T2 - 0.5f * ggp;

                float x0 = xs[ww][0], x1 = xs[ww][1], x2 = xs[ww][2];
                float x3 = xs[ww][3], x4 = xs[ww][4], x5 = xs[ww][5];
                float d01 = (x0-x1)*(x0-x1) + (x2-x1)*(x2-x1);
                float d02 = (x0-x2)*(x0-x2) + (x1-x2)*(x1-x2);
                float d12 = (x3-x5)*(x3-x5) + (x4-x5)*(x4-x5);
                float inter = GCONST * (expf(-2.f*d01) + expf(-2.f*d02) + expf(-2.f*d12));

                out[wg]             = kin + potp + inter;
                out[NWALK + wg]     = kin;
                out[2 * NWALK + wg] = potp;
                out[3 * NWALK + wg] = inter;
            }
        }
    }
}

extern "C" void kernel_launch(void* const* d_in, const int* in_sizes, int n_in,
                              void* d_out, int out_size, void* d_ws, size_t ws_size,
                              hipStream_t stream) {
    const float* x  = (const float*)d_in[0];
    const float* W1 = (const float*)d_in[1];
    const float* b1 = (const float*)d_in[2];
    const float* W2 = (const float*)d_in[3];
    const float* b2 = (const float*)d_in[4];
    const float* w3 = (const float*)d_in[5];
    float* out = (float*)d_out;

    char* ws = (char*)d_ws;
    _Float16* W2c = (_Float16*)(ws);                       // 128 KB
    _Float16* W1c = (_Float16*)(ws + 131072);              // 24 KB
    _Float16* t1h = (_Float16*)(ws + 155648);              // 2 MB
    _Float16* h1h = (_Float16*)(ws + 2252800);             // 2 MB
    _Float16* chv = (_Float16*)(ws + 4349952);             // 2 MB

    prep_all<<<16 + NWALK / 16, 256, 0, stream>>>(W2, W1, x, b1, W2c, W1c, t1h, h1h, chv);
    eloc8<<<NWALK / WPB, 256, 0, stream>>>(x, b2, w3, W2c, W1c, t1h, h1h, chv, out);
}